// Round 1
// baseline (732.189 us; speedup 1.0000x reference)
//
#include <hip/hip_runtime.h>

typedef unsigned short u16;
typedef __attribute__((ext_vector_type(8))) short short8;
typedef __attribute__((ext_vector_type(4))) float floatx4;

#define MFMA_BF16(a, b, c) __builtin_amdgcn_mfma_f32_16x16x32_bf16((a), (b), (c), 0, 0, 0)

__device__ __forceinline__ float bf2f(u16 u) {
  return __uint_as_float(((unsigned)u) << 16);
}
__device__ __forceinline__ u16 f2bf(float f) {
  unsigned b = __float_as_uint(f);
  b = b + 0x7FFFu + ((b >> 16) & 1u);
  return (u16)(b >> 16);
}

// ---------------- fp32 -> bf16 cast (x4 vectorized) ----------------
__global__ __launch_bounds__(256) void cast4_kernel(const float* __restrict__ src,
                                                    u16* __restrict__ dst, int n4) {
  int i = blockIdx.x * 256 + threadIdx.x;
  if (i < n4) {
    float4 v = ((const float4*)src)[i];
    ushort4 o;
    o.x = f2bf(v.x); o.y = f2bf(v.y); o.z = f2bf(v.z); o.w = f2bf(v.w);
    ((ushort4*)dst)[i] = o;
  }
}

// ---------------- LayerNorm (D=512), fp32 in -> bf16 out ----------------
__global__ __launch_bounds__(128) void ln_kernel(const float* __restrict__ x,
                                                 const float* __restrict__ g,
                                                 const float* __restrict__ be,
                                                 u16* __restrict__ y) {
  int row = blockIdx.x, t = threadIdx.x;
  float4 v = ((const float4*)(x + (size_t)row * 512))[t];
  float s = v.x + v.y + v.z + v.w;
  float q = v.x * v.x + v.y * v.y + v.z * v.z + v.w * v.w;
#pragma unroll
  for (int off = 32; off > 0; off >>= 1) {
    s += __shfl_xor(s, off);
    q += __shfl_xor(q, off);
  }
  __shared__ float sb[2], qb[2];
  int w = t >> 6;
  if ((t & 63) == 0) { sb[w] = s; qb[w] = q; }
  __syncthreads();
  s = sb[0] + sb[1];
  q = qb[0] + qb[1];
  float mu = s * (1.0f / 512.0f);
  float var = q * (1.0f / 512.0f) - mu * mu;
  float rs = rsqrtf(var + 1e-5f);
  float4 gg = ((const float4*)g)[t];
  float4 bb = ((const float4*)be)[t];
  ushort4 o;
  o.x = f2bf((v.x - mu) * rs * gg.x + bb.x);
  o.y = f2bf((v.y - mu) * rs * gg.y + bb.y);
  o.z = f2bf((v.z - mu) * rs * gg.z + bb.z);
  o.w = f2bf((v.w - mu) * rs * gg.w + bb.w);
  ((ushort4*)(y + (size_t)row * 512))[t] = o;
}

// ---------------- MFMA GEMM: C[M,N] = A[M,K] @ W[N,K]^T + bias (+res, +silu) ----
// block = 256 threads = 4 waves, each wave a 64x64 tile, block tile 128x128.
// Direct global frag loads (A and W both K-contiguous -> 16B/lane).
template <bool OUTB, bool SILU, bool RES>
__global__ __launch_bounds__(256) void gemm_bt_kernel(
    const u16* __restrict__ A, const u16* __restrict__ W,
    const float* __restrict__ bias, const float* __restrict__ res,
    void* __restrict__ out, int N, int K) {
  int lane = threadIdx.x & 63, wave = threadIdx.x >> 6;
  int l15 = lane & 15, quad = lane >> 4;
  int rowBlk = blockIdx.y * 128 + (wave >> 1) * 64;
  int colBlk = blockIdx.x * 128 + (wave & 1) * 64;
  const u16* Ap = A + (size_t)rowBlk * K;
  const u16* Wp = W + (size_t)colBlk * K;
  floatx4 acc[4][4] = {};
  for (int k0 = 0; k0 < K; k0 += 32) {
    int koff = k0 + quad * 8;
    short8 a[4], b[4];
#pragma unroll
    for (int i = 0; i < 4; ++i)
      a[i] = *(const short8*)(Ap + (size_t)(i * 16 + l15) * K + koff);
#pragma unroll
    for (int j = 0; j < 4; ++j)
      b[j] = *(const short8*)(Wp + (size_t)(j * 16 + l15) * K + koff);
#pragma unroll
    for (int i = 0; i < 4; ++i)
#pragma unroll
      for (int j = 0; j < 4; ++j)
        acc[i][j] = MFMA_BF16(a[i], b[j], acc[i][j]);
  }
#pragma unroll
  for (int j = 0; j < 4; ++j) {
    int col = colBlk + j * 16 + l15;
    float bs = bias[col];
#pragma unroll
    for (int i = 0; i < 4; ++i) {
      int row0 = rowBlk + i * 16 + quad * 4;
#pragma unroll
      for (int r = 0; r < 4; ++r) {
        size_t idx = (size_t)(row0 + r) * N + col;
        float v = acc[i][j][r] + bs;
        if (RES) v += res[idx];
        if (SILU) v = v * (1.0f / (1.0f + __expf(-v)));
        if (OUTB) ((u16*)out)[idx] = f2bf(v);
        else ((float*)out)[idx] = v;
      }
    }
  }
}

// ---------------- V transpose: qkv v-part [b][n][h][dh] -> vT [b][h][dh][n] ----
__global__ __launch_bounds__(256) void vtrans_kernel(const u16* __restrict__ qkv,
                                                     u16* __restrict__ vT) {
  __shared__ u16 tile[64][68];
  int blk = blockIdx.x;
  int b = blk >> 7, h = (blk >> 4) & 7, n0 = (blk & 15) * 64;
  int t = threadIdx.x;
#pragma unroll
  for (int rep = 0; rep < 16; ++rep) {
    int idx = t + rep * 256;
    int nl = idx >> 6, dh = idx & 63;
    tile[nl][dh] = qkv[(size_t)(b * 1024 + n0 + nl) * 1536 + 1024 + h * 64 + dh];
  }
  __syncthreads();
#pragma unroll
  for (int rep = 0; rep < 16; ++rep) {
    int idx = t + rep * 256;
    int dh = idx >> 6, nl = idx & 63;
    vT[((size_t)(b * 8 + h) * 64 + dh) * 1024 + n0 + nl] = tile[nl][dh];
  }
}

// ---------------- Fused attention ----------------
// Block = (b, 16 q-rows), 256 threads = 4 waves. Loops 8 heads.
// Per head: S strip 16x1024 via MFMA (wave w covers cols w*256..+255),
// e = exp(0.125*s) (no max-sub: |logit| <~ 6), row-sums via shuffles+LDS,
// unnormalized e -> bf16 LDS strip, PV via MFMA (A from LDS, B from vT global).
// attn mean-over-heads accumulates in registers (consistent lane mapping).
__global__ __launch_bounds__(256) void attn_kernel(const u16* __restrict__ qkv,
                                                   const u16* __restrict__ vT,
                                                   u16* __restrict__ ctx,
                                                   float* __restrict__ attnw) {
  __shared__ __align__(16) u16 es[16][1032];
  __shared__ float lsum[4][16];
  __shared__ float linv[16];
  int t = threadIdx.x;
  int lane = t & 63, wave = t >> 6;
  int l15 = lane & 15, quad = lane >> 4;
  int b = blockIdx.x >> 6, q0 = (blockIdx.x & 63) * 16;
  float avg[16][4];
#pragma unroll
  for (int i = 0; i < 16; ++i) {
    avg[i][0] = 0.f; avg[i][1] = 0.f; avg[i][2] = 0.f; avg[i][3] = 0.f;
  }
  size_t qrow = (size_t)(b * 1024 + q0 + l15) * 1536;
  int colbase = wave * 256;
#pragma unroll 1
  for (int h = 0; h < 8; ++h) {
    // ---- S = Q K^T (this wave: 16 rows x 256 cols) ----
    short8 qf0 = *(const short8*)(qkv + qrow + h * 64 + quad * 8);
    short8 qf1 = *(const short8*)(qkv + qrow + h * 64 + 32 + quad * 8);
    floatx4 sacc[16] = {};
#pragma unroll
    for (int tile = 0; tile < 16; ++tile) {
      const u16* kp = qkv + (size_t)(b * 1024 + colbase + tile * 16 + l15) * 1536 +
                      512 + h * 64 + quad * 8;
      short8 kf0 = *(const short8*)kp;
      short8 kf1 = *(const short8*)(kp + 32);
      sacc[tile] = MFMA_BF16(qf0, kf0, sacc[tile]);
      sacc[tile] = MFMA_BF16(qf1, kf1, sacc[tile]);
    }
    // ---- e = exp(s/8), partial row sums ----
    float part[4] = {0.f, 0.f, 0.f, 0.f};
#pragma unroll
    for (int tile = 0; tile < 16; ++tile)
#pragma unroll
      for (int r = 0; r < 4; ++r) {
        float e = __expf(sacc[tile][r] * 0.125f);
        sacc[tile][r] = e;
        part[r] += e;
      }
#pragma unroll
    for (int off = 1; off < 16; off <<= 1) {
#pragma unroll
      for (int r = 0; r < 4; ++r) part[r] += __shfl_xor(part[r], off);
    }
    if (l15 == 0) {
#pragma unroll
      for (int r = 0; r < 4; ++r) lsum[wave][quad * 4 + r] = part[r];
    }
    __syncthreads();
    if (t < 16) linv[t] = 1.0f / (lsum[0][t] + lsum[1][t] + lsum[2][t] + lsum[3][t]);
    __syncthreads();
    float il[4];
#pragma unroll
    for (int r = 0; r < 4; ++r) il[r] = linv[quad * 4 + r];
    // ---- accumulate avg (normalized), store unnormalized e as bf16 ----
#pragma unroll
    for (int tile = 0; tile < 16; ++tile)
#pragma unroll
      for (int r = 0; r < 4; ++r) {
        float e = sacc[tile][r];
        avg[tile][r] += e * il[r];
        es[quad * 4 + r][colbase + tile * 16 + l15] = f2bf(e);
      }
    __syncthreads();
    // ---- O = P V (wave handles dh-tile = wave*16..+15) ----
    floatx4 oacc = {};
    const u16* vb = vT + ((size_t)(b * 8 + h) * 64 + wave * 16 + l15) * 1024;
#pragma unroll
    for (int kk = 0; kk < 32; ++kk) {
      short8 af = *(const short8*)(&es[l15][kk * 32 + quad * 8]);
      short8 bf = *(const short8*)(vb + kk * 32 + quad * 8);
      oacc = MFMA_BF16(af, bf, oacc);
    }
#pragma unroll
    for (int r = 0; r < 4; ++r) {
      float o = oacc[r] * il[r];
      ctx[(size_t)(b * 1024 + q0 + quad * 4 + r) * 512 + h * 64 + wave * 16 + l15] =
          f2bf(o);
    }
    __syncthreads();
  }
  // ---- write averaged attention weights (x 1/H) ----
#pragma unroll
  for (int tile = 0; tile < 16; ++tile)
#pragma unroll
    for (int r = 0; r < 4; ++r)
      attnw[(size_t)(b * 1024 + q0 + quad * 4 + r) * 1024 + colbase + tile * 16 + l15] =
          avg[tile][r] * 0.125f;
}

// ---------------- host launch ----------------
extern "C" void kernel_launch(void* const* d_in, const int* in_sizes, int n_in,
                              void* d_out, int out_size, void* d_ws, size_t ws_size,
                              hipStream_t stream) {
  (void)in_sizes; (void)n_in; (void)out_size; (void)ws_size;
  const float* h   = (const float*)d_in[0];
  const float* g1  = (const float*)d_in[1];
  const float* be1 = (const float*)d_in[2];
  const float* wq  = (const float*)d_in[3];
  const float* bq  = (const float*)d_in[4];
  const float* wk  = (const float*)d_in[5];
  const float* bk  = (const float*)d_in[6];
  const float* wv  = (const float*)d_in[7];
  const float* bv  = (const float*)d_in[8];
  const float* wo  = (const float*)d_in[9];
  const float* bo  = (const float*)d_in[10];
  const float* g2  = (const float*)d_in[11];
  const float* be2 = (const float*)d_in[12];
  const float* w1  = (const float*)d_in[13];
  const float* b1  = (const float*)d_in[14];
  const float* w2  = (const float*)d_in[15];
  const float* b2  = (const float*)d_in[16];

  char* p = (char*)d_ws;
  auto carve = [&](size_t bytes) {
    char* r = p;
    p += (bytes + 255) & ~(size_t)255;
    return r;
  };
  u16*   wcat = (u16*)carve((size_t)1536 * 512 * 2);
  u16*   wob  = (u16*)carve((size_t)512 * 512 * 2);
  u16*   w1b  = (u16*)carve((size_t)1024 * 512 * 2);
  u16*   w2b  = (u16*)carve((size_t)512 * 1024 * 2);
  float* bcat = (float*)carve((size_t)1536 * 4);
  u16*   hn   = (u16*)carve((size_t)16384 * 512 * 2);
  u16*   qkvb = (u16*)carve((size_t)16384 * 1536 * 2);
  u16*   vTb  = (u16*)carve((size_t)16384 * 512 * 2);
  u16*   ctxb = (u16*)carve((size_t)16384 * 512 * 2);
  u16*   fb   = (u16*)carve((size_t)16384 * 512 * 2);
  u16*   gb   = (u16*)carve((size_t)16384 * 1024 * 2);

  float* outh = (float*)d_out;
  float* outattn = outh + (size_t)16384 * 512;

  // weight prep (bf16 casts + bias concat)
  cast4_kernel<<<256, 256, 0, stream>>>(wq, wcat, 65536);
  cast4_kernel<<<256, 256, 0, stream>>>(wk, wcat + 512 * 512, 65536);
  cast4_kernel<<<256, 256, 0, stream>>>(wv, wcat + 2 * 512 * 512, 65536);
  cast4_kernel<<<256, 256, 0, stream>>>(wo, wob, 65536);
  cast4_kernel<<<512, 256, 0, stream>>>(w1, w1b, 131072);
  cast4_kernel<<<512, 256, 0, stream>>>(w2, w2b, 131072);
  hipMemcpyAsync(bcat, bq, 512 * 4, hipMemcpyDeviceToDevice, stream);
  hipMemcpyAsync(bcat + 512, bk, 512 * 4, hipMemcpyDeviceToDevice, stream);
  hipMemcpyAsync(bcat + 1024, bv, 512 * 4, hipMemcpyDeviceToDevice, stream);

  // LN1 -> hn(bf16)
  ln_kernel<<<16384, 128, 0, stream>>>(h, g1, be1, hn);
  // QKV: [16384,1536] = hn @ wcat^T + bcat  (bf16 out)
  gemm_bt_kernel<true, false, false><<<dim3(12, 128), 256, 0, stream>>>(
      hn, wcat, bcat, nullptr, qkvb, 1536, 512);
  // V transpose for PV MFMA B-operand
  vtrans_kernel<<<2048, 256, 0, stream>>>(qkvb, vTb);
  // attention: ctx(bf16) + averaged attn weights (fp32, d_out tail)
  attn_kernel<<<1024, 256, 0, stream>>>(qkvb, vTb, ctxb, outattn);
  // out-proj + residual(h) -> d_out head region (fp32 h2)
  gemm_bt_kernel<false, false, true><<<dim3(4, 128), 256, 0, stream>>>(
      ctxb, wob, bo, h, outh, 512, 512);
  // LN2(h2) -> fb(bf16)
  ln_kernel<<<16384, 128, 0, stream>>>(outh, g2, be2, fb);
  // FFN1 + SiLU -> gb(bf16)
  gemm_bt_kernel<true, true, false><<<dim3(8, 128), 256, 0, stream>>>(
      fb, w1b, b1, nullptr, gb, 1024, 512);
  // FFN2 + residual(h2) -> final h (fp32, in place on d_out)
  gemm_bt_kernel<false, false, true><<<dim3(4, 128), 256, 0, stream>>>(
      gb, w2b, b2, outh, outh, 512, 1024);
}

// Round 2
// 705.511 us; speedup vs baseline: 1.0378x; 1.0378x over previous
//
#include <hip/hip_runtime.h>

typedef unsigned short u16;
typedef __attribute__((ext_vector_type(8))) short short8;
typedef __attribute__((ext_vector_type(4))) float floatx4;

#define MFMA_BF16(a, b, c) __builtin_amdgcn_mfma_f32_16x16x32_bf16((a), (b), (c), 0, 0, 0)

__device__ __forceinline__ u16 f2bf(float f) {
  unsigned b = __float_as_uint(f);
  b = b + 0x7FFFu + ((b >> 16) & 1u);
  return (u16)(b >> 16);
}

// async global->LDS, 16B per lane. lds ptr MUST be wave-uniform; HW scatters
// lane i's 16B to lds_base + i*16.
__device__ __forceinline__ void gll16(const u16* g, u16* lds_uniform) {
  __builtin_amdgcn_global_load_lds(
      (const __attribute__((address_space(1))) void*)g,
      (__attribute__((address_space(3))) void*)lds_uniform, 16, 0, 0);
}

// ---------------- fp32 -> bf16 cast (x4 vectorized) ----------------
__global__ __launch_bounds__(256) void cast4_kernel(const float* __restrict__ src,
                                                    u16* __restrict__ dst, int n4) {
  int i = blockIdx.x * 256 + threadIdx.x;
  if (i < n4) {
    float4 v = ((const float4*)src)[i];
    ushort4 o;
    o.x = f2bf(v.x); o.y = f2bf(v.y); o.z = f2bf(v.z); o.w = f2bf(v.w);
    ((ushort4*)dst)[i] = o;
  }
}

// ---------------- LayerNorm (D=512), fp32 in -> bf16 out ----------------
__global__ __launch_bounds__(128) void ln_kernel(const float* __restrict__ x,
                                                 const float* __restrict__ g,
                                                 const float* __restrict__ be,
                                                 u16* __restrict__ y) {
  int row = blockIdx.x, t = threadIdx.x;
  float4 v = ((const float4*)(x + (size_t)row * 512))[t];
  float s = v.x + v.y + v.z + v.w;
  float q = v.x * v.x + v.y * v.y + v.z * v.z + v.w * v.w;
#pragma unroll
  for (int off = 32; off > 0; off >>= 1) {
    s += __shfl_xor(s, off);
    q += __shfl_xor(q, off);
  }
  __shared__ float sb[2], qb[2];
  int w = t >> 6;
  if ((t & 63) == 0) { sb[w] = s; qb[w] = q; }
  __syncthreads();
  s = sb[0] + sb[1];
  q = qb[0] + qb[1];
  float mu = s * (1.0f / 512.0f);
  float var = q * (1.0f / 512.0f) - mu * mu;
  float rs = rsqrtf(var + 1e-5f);
  float4 gg = ((const float4*)g)[t];
  float4 bb = ((const float4*)be)[t];
  ushort4 o;
  o.x = f2bf((v.x - mu) * rs * gg.x + bb.x);
  o.y = f2bf((v.y - mu) * rs * gg.y + bb.y);
  o.z = f2bf((v.z - mu) * rs * gg.z + bb.z);
  o.w = f2bf((v.w - mu) * rs * gg.w + bb.w);
  ((ushort4*)(y + (size_t)row * 512))[t] = o;
}

// ---------------- m97-style MFMA GEMM: C = A @ W^T + bias (+res, +silu) ----
// 256 thr = 4 waves, block tile 128x128, BK=32, LDS staging via global_load_lds.
template <bool OUTB, bool SILU, bool RES>
__global__ __launch_bounds__(256) void gemm_bt_kernel(
    const u16* __restrict__ A, const u16* __restrict__ W,
    const float* __restrict__ bias, const float* __restrict__ res,
    void* __restrict__ out, int N, int K) {
  __shared__ __align__(16) u16 As[128 * 32];
  __shared__ __align__(16) u16 Bs[128 * 32];
  int t = threadIdx.x;
  int lane = t & 63, wave = t >> 6;
  int l15 = lane & 15, quad = lane >> 4;
  int rowBlk = blockIdx.y * 128, colBlk = blockIdx.x * 128;
  // staging: thread t loads 16B = row (t>>2), cols (t&3)*8 of the 128x32 tile
  const u16* Ag = A + (size_t)(rowBlk + (t >> 2)) * K + (t & 3) * 8;
  const u16* Wg = W + (size_t)(colBlk + (t >> 2)) * K + (t & 3) * 8;
  u16* AsW = As + wave * 512;   // wave-uniform LDS base (1024 B per wave-issue)
  u16* BsW = Bs + wave * 512;
  int arow = (wave >> 1) * 64;  // this wave's 64x64 tile
  int brow = (wave & 1) * 64;
  floatx4 acc[4][4] = {};
  for (int k0 = 0; k0 < K; k0 += 32) {
    gll16(Ag + k0, AsW);
    gll16(Ag + (size_t)64 * K + k0, AsW + 2048);
    gll16(Wg + k0, BsW);
    gll16(Wg + (size_t)64 * K + k0, BsW + 2048);
    __syncthreads();
    short8 a[4], b[4];
#pragma unroll
    for (int i = 0; i < 4; ++i)
      a[i] = *(const short8*)(As + (size_t)(arow + i * 16 + l15) * 32 + quad * 8);
#pragma unroll
    for (int j = 0; j < 4; ++j)
      b[j] = *(const short8*)(Bs + (size_t)(brow + j * 16 + l15) * 32 + quad * 8);
#pragma unroll
    for (int i = 0; i < 4; ++i)
#pragma unroll
      for (int j = 0; j < 4; ++j)
        acc[i][j] = MFMA_BF16(a[i], b[j], acc[i][j]);
    __syncthreads();
  }
#pragma unroll
  for (int j = 0; j < 4; ++j) {
    int col = colBlk + brow + j * 16 + l15;
    float bs = bias[col];
#pragma unroll
    for (int i = 0; i < 4; ++i) {
      int row0 = rowBlk + arow + i * 16 + quad * 4;
#pragma unroll
      for (int r = 0; r < 4; ++r) {
        size_t idx = (size_t)(row0 + r) * N + col;
        float v = acc[i][j][r] + bs;
        if (RES) v += res[idx];
        if (SILU) v = v * (1.0f / (1.0f + __expf(-v)));
        if (OUTB) ((u16*)out)[idx] = f2bf(v);
        else ((float*)out)[idx] = v;
      }
    }
  }
}

// ---------------- V transpose: qkv v-part [b][n][h][dh] -> vT [b][h][dh][n] ----
__global__ __launch_bounds__(256) void vtrans_kernel(const u16* __restrict__ qkv,
                                                     u16* __restrict__ vT) {
  __shared__ u16 tile[64][68];
  int blk = blockIdx.x;
  int b = blk >> 7, h = (blk >> 4) & 7, n0 = (blk & 15) * 64;
  int t = threadIdx.x;
#pragma unroll
  for (int rep = 0; rep < 16; ++rep) {
    int idx = t + rep * 256;
    int nl = idx >> 6, dh = idx & 63;
    tile[nl][dh] = qkv[(size_t)(b * 1024 + n0 + nl) * 1536 + 1024 + h * 64 + dh];
  }
  __syncthreads();
#pragma unroll
  for (int rep = 0; rep < 16; ++rep) {
    int idx = t + rep * 256;
    int dh = idx >> 6, nl = idx & 63;
    vT[((size_t)(b * 8 + h) * 64 + dh) * 1024 + n0 + nl] = tile[nl][dh];
  }
}

// ---------------- attention ctx (flash-style, ZERO barriers) ----------------
// block = (qblk64, h, b), 4 waves, wave owns 16 q-rows for the full col range.
// Per 64-col chunk: S via MFMA (K direct from global), exp (no max-sub: |logit|
// <~6), rowsum accum in regs, e->bf16 into wave-PRIVATE LDS (granule-major
// layout so PV A-frag reads are b128-contiguous), PV via MFMA (vT B-operand).
// Row-sum reduce via shfl_xor within the 16-lane group; O normalized at end.
__global__ __launch_bounds__(256) void attn_ctx_kernel(const u16* __restrict__ qkv,
                                                       const u16* __restrict__ vT,
                                                       u16* __restrict__ ctx) {
  // per-wave 2KB: [8 granules][16 rows][8 cols] u16
  __shared__ __align__(16) u16 es[4][1024];
  int t = threadIdx.x, lane = t & 63, wave = t >> 6;
  int l15 = lane & 15, quad = lane >> 4;
  int b = blockIdx.z, h = blockIdx.y, q0 = blockIdx.x * 64 + wave * 16;
  u16* esw = &es[wave][0];
  const u16* qbase = qkv + (size_t)(b * 1024 + q0 + l15) * 1536 + h * 64;
  short8 qf0 = *(const short8*)(qbase + quad * 8);
  short8 qf1 = *(const short8*)(qbase + 32 + quad * 8);
  floatx4 oacc[4] = {};
  float rs[4] = {0.f, 0.f, 0.f, 0.f};
  const u16* vrow = vT + ((size_t)(b * 8 + h) * 64 + l15) * 1024;
#pragma unroll 1
  for (int c0 = 0; c0 < 1024; c0 += 64) {
    // S: 4 col-tiles of 16
    floatx4 s[4] = {};
    const u16* kbase =
        qkv + (size_t)(b * 1024 + c0 + l15) * 1536 + 512 + h * 64 + quad * 8;
#pragma unroll
    for (int ct = 0; ct < 4; ++ct) {
      short8 kf0 = *(const short8*)(kbase + (size_t)ct * 16 * 1536);
      short8 kf1 = *(const short8*)(kbase + (size_t)ct * 16 * 1536 + 32);
      s[ct] = MFMA_BF16(qf0, kf0, s[ct]);
      s[ct] = MFMA_BF16(qf1, kf1, s[ct]);
    }
    // exp + rowsum + store e (granule-major: granule g holds cols g*8..+8)
#pragma unroll
    for (int ct = 0; ct < 4; ++ct)
#pragma unroll
      for (int r = 0; r < 4; ++r) {
        float e = __expf(s[ct][r] * 0.125f);
        rs[r] += e;
        esw[((ct * 2 + (l15 >> 3)) * 16 + quad * 4 + r) * 8 + (l15 & 7)] = f2bf(e);
      }
    // PV: O[16x64] += P[16x64] @ V[64x64]  (wave-private LDS; in-order DS pipe)
#pragma unroll
    for (int ks = 0; ks < 2; ++ks) {
      short8 af = *(const short8*)(esw + ((ks * 4 + quad) * 16 + l15) * 8);
      const u16* vb = vrow + c0 + ks * 32 + quad * 8;
#pragma unroll
      for (int d = 0; d < 4; ++d) {
        short8 vf = *(const short8*)(vb + (size_t)d * 16 * 1024);
        oacc[d] = MFMA_BF16(af, vf, oacc[d]);
      }
    }
  }
#pragma unroll
  for (int off = 1; off < 16; off <<= 1)
#pragma unroll
    for (int r = 0; r < 4; ++r) rs[r] += __shfl_xor(rs[r], off);
#pragma unroll
  for (int r = 0; r < 4; ++r) {
    float il = 1.0f / rs[r];
    size_t row = (size_t)(b * 1024 + q0 + quad * 4 + r);
#pragma unroll
    for (int d = 0; d < 4; ++d)
      ctx[row * 512 + h * 64 + d * 16 + l15] = f2bf(oacc[d][r] * il);
  }
}

// ---------------- averaged attention weights ----------------
// block = (b, 16 q-rows), 512 thr = 8 waves x 128-col strips. Loops 8 heads;
// one barrier per head (double-buffered lsum). Writes mean_h softmax /8.
__global__ __launch_bounds__(512) void attn_avg_kernel(const u16* __restrict__ qkv,
                                                       float* __restrict__ attnw) {
  __shared__ float lsum[2][8][16];
  int t = threadIdx.x, lane = t & 63, wave = t >> 6;
  int l15 = lane & 15, quad = lane >> 4;
  int b = blockIdx.x >> 6, q0 = (blockIdx.x & 63) * 16;
  int colbase = wave * 128;
  floatx4 avg[8] = {};
  size_t qrow = (size_t)(b * 1024 + q0 + l15) * 1536;
#pragma unroll 1
  for (int h = 0; h < 8; ++h) {
    short8 qf0 = *(const short8*)(qkv + qrow + h * 64 + quad * 8);
    short8 qf1 = *(const short8*)(qkv + qrow + h * 64 + 32 + quad * 8);
    floatx4 sacc[8] = {};
#pragma unroll
    for (int tile = 0; tile < 8; ++tile) {
      const u16* kp = qkv + (size_t)(b * 1024 + colbase + tile * 16 + l15) * 1536 +
                      512 + h * 64 + quad * 8;
      short8 kf0 = *(const short8*)kp;
      short8 kf1 = *(const short8*)(kp + 32);
      sacc[tile] = MFMA_BF16(qf0, kf0, sacc[tile]);
      sacc[tile] = MFMA_BF16(qf1, kf1, sacc[tile]);
    }
    float part[4] = {0.f, 0.f, 0.f, 0.f};
#pragma unroll
    for (int tile = 0; tile < 8; ++tile)
#pragma unroll
      for (int r = 0; r < 4; ++r) {
        float e = __expf(sacc[tile][r] * 0.125f);
        sacc[tile][r] = e;
        part[r] += e;
      }
#pragma unroll
    for (int off = 1; off < 16; off <<= 1)
#pragma unroll
      for (int r = 0; r < 4; ++r) part[r] += __shfl_xor(part[r], off);
    int hb = h & 1;
    if (l15 == 0) {
#pragma unroll
      for (int r = 0; r < 4; ++r) lsum[hb][wave][quad * 4 + r] = part[r];
    }
    __syncthreads();
#pragma unroll
    for (int r = 0; r < 4; ++r) {
      int qr = quad * 4 + r;
      float sum = lsum[hb][0][qr] + lsum[hb][1][qr] + lsum[hb][2][qr] +
                  lsum[hb][3][qr] + lsum[hb][4][qr] + lsum[hb][5][qr] +
                  lsum[hb][6][qr] + lsum[hb][7][qr];
      float il = 1.0f / sum;
#pragma unroll
      for (int tile = 0; tile < 8; ++tile) avg[tile][r] += sacc[tile][r] * il;
    }
  }
#pragma unroll
  for (int tile = 0; tile < 8; ++tile)
#pragma unroll
    for (int r = 0; r < 4; ++r)
      attnw[(size_t)(b * 1024 + q0 + quad * 4 + r) * 1024 + colbase + tile * 16 +
            l15] = avg[tile][r] * 0.125f;
}

// ---------------- host launch ----------------
extern "C" void kernel_launch(void* const* d_in, const int* in_sizes, int n_in,
                              void* d_out, int out_size, void* d_ws, size_t ws_size,
                              hipStream_t stream) {
  (void)in_sizes; (void)n_in; (void)out_size; (void)ws_size;
  const float* h   = (const float*)d_in[0];
  const float* g1  = (const float*)d_in[1];
  const float* be1 = (const float*)d_in[2];
  const float* wq  = (const float*)d_in[3];
  const float* bq  = (const float*)d_in[4];
  const float* wk  = (const float*)d_in[5];
  const float* bk  = (const float*)d_in[6];
  const float* wv  = (const float*)d_in[7];
  const float* bv  = (const float*)d_in[8];
  const float* wo  = (const float*)d_in[9];
  const float* bo  = (const float*)d_in[10];
  const float* g2  = (const float*)d_in[11];
  const float* be2 = (const float*)d_in[12];
  const float* w1  = (const float*)d_in[13];
  const float* b1  = (const float*)d_in[14];
  const float* w2  = (const float*)d_in[15];
  const float* b2  = (const float*)d_in[16];

  char* p = (char*)d_ws;
  auto carve = [&](size_t bytes) {
    char* r = p;
    p += (bytes + 255) & ~(size_t)255;
    return r;
  };
  u16*   wcat = (u16*)carve((size_t)1536 * 512 * 2);
  u16*   wob  = (u16*)carve((size_t)512 * 512 * 2);
  u16*   w1b  = (u16*)carve((size_t)1024 * 512 * 2);
  u16*   w2b  = (u16*)carve((size_t)512 * 1024 * 2);
  float* bcat = (float*)carve((size_t)1536 * 4);
  u16*   hn   = (u16*)carve((size_t)16384 * 512 * 2);
  u16*   qkvb = (u16*)carve((size_t)16384 * 1536 * 2);
  u16*   vTb  = (u16*)carve((size_t)16384 * 512 * 2);
  u16*   ctxb = (u16*)carve((size_t)16384 * 512 * 2);
  u16*   fb   = (u16*)carve((size_t)16384 * 512 * 2);
  u16*   gb   = (u16*)carve((size_t)16384 * 1024 * 2);

  float* outh = (float*)d_out;
  float* outattn = outh + (size_t)16384 * 512;

  // weight prep (bf16 casts + bias concat)
  cast4_kernel<<<256, 256, 0, stream>>>(wq, wcat, 65536);
  cast4_kernel<<<256, 256, 0, stream>>>(wk, wcat + 512 * 512, 65536);
  cast4_kernel<<<256, 256, 0, stream>>>(wv, wcat + 2 * 512 * 512, 65536);
  cast4_kernel<<<256, 256, 0, stream>>>(wo, wob, 65536);
  cast4_kernel<<<512, 256, 0, stream>>>(w1, w1b, 131072);
  cast4_kernel<<<512, 256, 0, stream>>>(w2, w2b, 131072);
  hipMemcpyAsync(bcat, bq, 512 * 4, hipMemcpyDeviceToDevice, stream);
  hipMemcpyAsync(bcat + 512, bk, 512 * 4, hipMemcpyDeviceToDevice, stream);
  hipMemcpyAsync(bcat + 1024, bv, 512 * 4, hipMemcpyDeviceToDevice, stream);

  // LN1 -> hn(bf16)
  ln_kernel<<<16384, 128, 0, stream>>>(h, g1, be1, hn);
  // QKV: [16384,1536] = hn @ wcat^T + bcat  (bf16 out)
  gemm_bt_kernel<true, false, false><<<dim3(12, 128), 256, 0, stream>>>(
      hn, wcat, bcat, nullptr, qkvb, 1536, 512);
  // V transpose for PV MFMA B-operand
  vtrans_kernel<<<2048, 256, 0, stream>>>(qkvb, vTb);
  // attention context (no barriers) + averaged weights (separate kernel)
  attn_ctx_kernel<<<dim3(16, 8, 16), 256, 0, stream>>>(qkvb, vTb, ctxb);
  attn_avg_kernel<<<1024, 512, 0, stream>>>(qkvb, outattn);
  // out-proj + residual(h) -> d_out head region (fp32 h2)
  gemm_bt_kernel<false, false, true><<<dim3(4, 128), 256, 0, stream>>>(
      ctxb, wob, bo, h, outh, 512, 512);
  // LN2(h2) -> fb(bf16)
  ln_kernel<<<16384, 128, 0, stream>>>(outh, g2, be2, fb);
  // FFN1 + SiLU -> gb(bf16)
  gemm_bt_kernel<true, true, false><<<dim3(8, 128), 256, 0, stream>>>(
      fb, w1b, b1, nullptr, gb, 1024, 512);
  // FFN2 + residual(h2) -> final h (fp32, in place on d_out)
  gemm_bt_kernel<false, false, true><<<dim3(4, 128), 256, 0, stream>>>(
      gb, w2b, b2, outh, outh, 512, 1024);
}

// Round 3
// 552.768 us; speedup vs baseline: 1.3246x; 1.2763x over previous
//
#include <hip/hip_runtime.h>

typedef unsigned short u16;
typedef __attribute__((ext_vector_type(8))) short short8;
typedef __attribute__((ext_vector_type(4))) float floatx4;
typedef __attribute__((ext_vector_type(16))) float floatx16;

#define MFMA_BF16(a, b, c) __builtin_amdgcn_mfma_f32_16x16x32_bf16((a), (b), (c), 0, 0, 0)
#define MFMA32(a, b, c) __builtin_amdgcn_mfma_f32_32x32x16_bf16((a), (b), (c), 0, 0, 0)

__device__ __forceinline__ u16 f2bf(float f) {
  unsigned b = __float_as_uint(f);
  b = b + 0x7FFFu + ((b >> 16) & 1u);
  return (u16)(b >> 16);
}

// async global->LDS, 16B/lane; lds ptr is wave-uniform base, lane i lands at +i*16B
__device__ __forceinline__ void gll16(const u16* g, u16* lds_uniform) {
  __builtin_amdgcn_global_load_lds(
      (const __attribute__((address_space(1))) void*)g,
      (__attribute__((address_space(3))) void*)lds_uniform, 16, 0, 0);
}

// ---------------- fp32 -> bf16 cast ----------------
__global__ __launch_bounds__(256) void cast4_kernel(const float* __restrict__ src,
                                                    u16* __restrict__ dst, int n4) {
  int i = blockIdx.x * 256 + threadIdx.x;
  if (i < n4) {
    float4 v = ((const float4*)src)[i];
    ushort4 o;
    o.x = f2bf(v.x); o.y = f2bf(v.y); o.z = f2bf(v.z); o.w = f2bf(v.w);
    ((ushort4*)dst)[i] = o;
  }
}

// ---------------- LayerNorm (D=512), fp32 in -> bf16 out ----------------
__global__ __launch_bounds__(128) void ln_kernel(const float* __restrict__ x,
                                                 const float* __restrict__ g,
                                                 const float* __restrict__ be,
                                                 u16* __restrict__ y) {
  int row = blockIdx.x, t = threadIdx.x;
  float4 v = ((const float4*)(x + (size_t)row * 512))[t];
  float s = v.x + v.y + v.z + v.w;
  float q = v.x * v.x + v.y * v.y + v.z * v.z + v.w * v.w;
#pragma unroll
  for (int off = 32; off > 0; off >>= 1) {
    s += __shfl_xor(s, off);
    q += __shfl_xor(q, off);
  }
  __shared__ float sb[2], qb[2];
  int w = t >> 6;
  if ((t & 63) == 0) { sb[w] = s; qb[w] = q; }
  __syncthreads();
  s = sb[0] + sb[1];
  q = qb[0] + qb[1];
  float mu = s * (1.0f / 512.0f);
  float var = q * (1.0f / 512.0f) - mu * mu;
  float rs = rsqrtf(var + 1e-5f);
  float4 gg = ((const float4*)g)[t];
  float4 bb = ((const float4*)be)[t];
  ushort4 o;
  o.x = f2bf((v.x - mu) * rs * gg.x + bb.x);
  o.y = f2bf((v.y - mu) * rs * gg.y + bb.y);
  o.z = f2bf((v.z - mu) * rs * gg.z + bb.z);
  o.w = f2bf((v.w - mu) * rs * gg.w + bb.w);
  ((ushort4*)(y + (size_t)row * 512))[t] = o;
}

// ---------------- m97-style MFMA GEMM ----------------
template <bool OUTB, bool SILU, bool RES>
__global__ __launch_bounds__(256) void gemm_bt_kernel(
    const u16* __restrict__ A, const u16* __restrict__ W,
    const float* __restrict__ bias, const float* __restrict__ res,
    void* __restrict__ out, int N, int K) {
  __shared__ __align__(16) u16 As[128 * 32];
  __shared__ __align__(16) u16 Bs[128 * 32];
  int t = threadIdx.x;
  int lane = t & 63, wave = t >> 6;
  int l15 = lane & 15, quad = lane >> 4;
  int rowBlk = blockIdx.y * 128, colBlk = blockIdx.x * 128;
  const u16* Ag = A + (size_t)(rowBlk + (t >> 2)) * K + (t & 3) * 8;
  const u16* Wg = W + (size_t)(colBlk + (t >> 2)) * K + (t & 3) * 8;
  u16* AsW = As + wave * 512;
  u16* BsW = Bs + wave * 512;
  int arow = (wave >> 1) * 64;
  int brow = (wave & 1) * 64;
  floatx4 acc[4][4] = {};
  for (int k0 = 0; k0 < K; k0 += 32) {
    gll16(Ag + k0, AsW);
    gll16(Ag + (size_t)64 * K + k0, AsW + 2048);
    gll16(Wg + k0, BsW);
    gll16(Wg + (size_t)64 * K + k0, BsW + 2048);
    __syncthreads();
    short8 a[4], b[4];
#pragma unroll
    for (int i = 0; i < 4; ++i)
      a[i] = *(const short8*)(As + (size_t)(arow + i * 16 + l15) * 32 + quad * 8);
#pragma unroll
    for (int j = 0; j < 4; ++j)
      b[j] = *(const short8*)(Bs + (size_t)(brow + j * 16 + l15) * 32 + quad * 8);
#pragma unroll
    for (int i = 0; i < 4; ++i)
#pragma unroll
      for (int j = 0; j < 4; ++j)
        acc[i][j] = MFMA_BF16(a[i], b[j], acc[i][j]);
    __syncthreads();
  }
#pragma unroll
  for (int j = 0; j < 4; ++j) {
    int col = colBlk + brow + j * 16 + l15;
    float bs = bias[col];
#pragma unroll
    for (int i = 0; i < 4; ++i) {
      int row0 = rowBlk + arow + i * 16 + quad * 4;
#pragma unroll
      for (int r = 0; r < 4; ++r) {
        size_t idx = (size_t)(row0 + r) * N + col;
        float v = acc[i][j][r] + bs;
        if (RES) v += res[idx];
        if (SILU) v = v * (1.0f / (1.0f + __expf(-v)));
        if (OUTB) ((u16*)out)[idx] = f2bf(v);
        else ((float*)out)[idx] = v;
      }
    }
  }
}

// ---------------- V transpose: qkv v-part -> vT [b][h][dh][n] ----------------
__global__ __launch_bounds__(256) void vtrans_kernel(const u16* __restrict__ qkv,
                                                     u16* __restrict__ vT) {
  __shared__ u16 tile[64][68];
  int blk = blockIdx.x;
  int b = blk >> 7, h = (blk >> 4) & 7, n0 = (blk & 15) * 64;
  int t = threadIdx.x;
#pragma unroll
  for (int rep = 0; rep < 16; ++rep) {
    int idx = t + rep * 256;
    int nl = idx >> 6, dh = idx & 63;
    tile[nl][dh] = qkv[(size_t)(b * 1024 + n0 + nl) * 1536 + 1024 + h * 64 + dh];
  }
  __syncthreads();
#pragma unroll
  for (int rep = 0; rep < 16; ++rep) {
    int idx = t + rep * 256;
    int dh = idx >> 6, nl = idx & 63;
    vT[((size_t)(b * 8 + h) * 64 + dh) * 1024 + n0 + nl] = tile[nl][dh];
  }
}

// ---------------- attention ctx v3: 32x32 MFMA + LDS dbuf staging ----------------
// block = (qblk128, h, b), 4 waves x 32 q-rows. 16 key-chunks of 64.
// K/V staged block-wide via global_load_lds (double-buffered, 1 barrier/chunk).
// LDS layouts (granule = 8 u16 = 16B):
//   Kb[g=dh-gran 0..7][key 0..63][8]   Vb[g=key-gran 0..7][dh 0..63][8]
//   P (per wave): [g=key-gran 0..7][row^g 0..31][8]  (XOR swizzle: writes 2-way)
// Exports linv[b][h][q] = 1/rowsum for the avg kernel.
__global__ __launch_bounds__(256) void attn_ctx_kernel(const u16* __restrict__ qkv,
                                                       const u16* __restrict__ vT,
                                                       u16* __restrict__ ctx,
                                                       float* __restrict__ linv_g) {
  __shared__ __align__(16) u16 Kb[2][4096];
  __shared__ __align__(16) u16 Vb[2][4096];
  __shared__ __align__(16) u16 Pbuf[4][2048];
  int t = threadIdx.x, lane = t & 63, wave = t >> 6;
  int l31 = lane & 31, hi = lane >> 5;
  int b = blockIdx.z, h = blockIdx.y, q0w = blockIdx.x * 128 + wave * 32;
  u16* Pw = &Pbuf[wave][0];

  // Q fragments: lane l31 = q-row, k(dh) = t4*16 + hi*8 + j
  short8 qf[4];
  const u16* qbase = qkv + (size_t)(b * 1024 + q0w + l31) * 1536 + h * 64;
#pragma unroll
  for (int t4 = 0; t4 < 4; ++t4)
    qf[t4] = *(const short8*)(qbase + t4 * 16 + hi * 8);

  floatx16 oacc[2] = {};
  float rs[16];
#pragma unroll
  for (int r = 0; r < 16; ++r) rs[r] = 0.f;

  const u16* krow = qkv + (size_t)(b * 1024 + lane) * 1536 + 512 + h * 64;
  const u16* vrow = vT + ((size_t)(b * 8 + h) * 64 + lane) * 1024;

  // prologue stage chunk 0 into buf 0
  gll16(krow + wave * 8, &Kb[0][wave * 512]);
  gll16(krow + (wave + 4) * 8, &Kb[0][(wave + 4) * 512]);
  gll16(vrow + wave * 8, &Vb[0][wave * 512]);
  gll16(vrow + (wave + 4) * 8, &Vb[0][(wave + 4) * 512]);
  __syncthreads();

#pragma unroll 1
  for (int c = 0; c < 16; ++c) {
    int bf = c & 1;
    if (c < 15) {  // prefetch next chunk (async; drained by end-of-loop barrier)
      int nc = (c + 1) * 64;
      gll16(krow + (size_t)nc * 1536 + wave * 8, &Kb[bf ^ 1][wave * 512]);
      gll16(krow + (size_t)nc * 1536 + (wave + 4) * 8, &Kb[bf ^ 1][(wave + 4) * 512]);
      gll16(vrow + nc + wave * 8, &Vb[bf ^ 1][wave * 512]);
      gll16(vrow + nc + (wave + 4) * 8, &Vb[bf ^ 1][(wave + 4) * 512]);
    }
    // S = Q K^T : 2 key-tiles x 4 dh-steps
    floatx16 sacc[2] = {};
#pragma unroll
    for (int ct = 0; ct < 2; ++ct)
#pragma unroll
      for (int t4 = 0; t4 < 4; ++t4) {
        short8 kf = *(const short8*)&Kb[bf][(t4 * 2 + hi) * 512 + (ct * 32 + l31) * 8];
        sacc[ct] = MFMA32(qf[t4], kf, sacc[ct]);
      }
    // exp, rowsum accumulate, P -> wave-private LDS (xor-swizzled)
#pragma unroll
    for (int ct = 0; ct < 2; ++ct) {
      int key = ct * 32 + l31;
      int g = key >> 3;
      int kb = key & 7;
#pragma unroll
      for (int reg = 0; reg < 16; ++reg) {
        int row = (reg & 3) + 8 * (reg >> 2) + 4 * hi;
        float e = __expf(sacc[ct][reg] * 0.125f);
        rs[reg] += e;
        Pw[g * 256 + ((row ^ g) << 3) + kb] = f2bf(e);
      }
    }
    // O += P V : 4 key-steps x 2 dh-tiles
#pragma unroll
    for (int ks = 0; ks < 4; ++ks) {
      int g = ks * 2 + hi;
      short8 af = *(const short8*)&Pw[g * 256 + ((l31 ^ g) << 3)];
#pragma unroll
      for (int ct = 0; ct < 2; ++ct) {
        short8 vf = *(const short8*)&Vb[bf][g * 512 + (ct * 32 + l31) * 8];
        oacc[ct] = MFMA32(af, vf, oacc[ct]);
      }
    }
    __syncthreads();
  }

  // final rowsum reduce across the 32 key-lanes (hi halves hold disjoint rows)
#pragma unroll
  for (int off = 1; off < 32; off <<= 1)
#pragma unroll
    for (int r = 0; r < 16; ++r) rs[r] += __shfl_xor(rs[r], off);
  float il[16];
#pragma unroll
  for (int r = 0; r < 16; ++r) il[r] = 1.0f / rs[r];
  if (l31 == 0) {
#pragma unroll
    for (int reg = 0; reg < 16; ++reg) {
      int row = (reg & 3) + 8 * (reg >> 2) + 4 * hi;
      linv_g[(size_t)(b * 8 + h) * 1024 + q0w + row] = il[reg];
    }
  }
#pragma unroll
  for (int ct = 0; ct < 2; ++ct)
#pragma unroll
    for (int reg = 0; reg < 16; ++reg) {
      int row = (reg & 3) + 8 * (reg >> 2) + 4 * hi;
      ctx[(size_t)(b * 1024 + q0w + row) * 512 + h * 64 + ct * 32 + l31] =
          f2bf(oacc[ct][reg] * il[reg]);
    }
}

// ---------------- averaged attention weights (consumes linv; no barriers) ----
__global__ __launch_bounds__(512) void attn_avg_kernel(const u16* __restrict__ qkv,
                                                       const float* __restrict__ linv_g,
                                                       float* __restrict__ attnw) {
  int t = threadIdx.x, lane = t & 63, wave = t >> 6;
  int l15 = lane & 15, quad = lane >> 4;
  int b = blockIdx.x >> 6, q0 = (blockIdx.x & 63) * 16;
  int colbase = wave * 128;
  floatx4 avg[8] = {};
  size_t qrow = (size_t)(b * 1024 + q0 + l15) * 1536;
#pragma unroll 2
  for (int h = 0; h < 8; ++h) {
    short8 qf0 = *(const short8*)(qkv + qrow + h * 64 + quad * 8);
    short8 qf1 = *(const short8*)(qkv + qrow + h * 64 + 32 + quad * 8);
    float4 il4 = *(const float4*)&linv_g[(size_t)(b * 8 + h) * 1024 + q0 + quad * 4];
    float il[4] = {il4.x, il4.y, il4.z, il4.w};
    floatx4 sacc[8] = {};
#pragma unroll
    for (int tile = 0; tile < 8; ++tile) {
      const u16* kp = qkv + (size_t)(b * 1024 + colbase + tile * 16 + l15) * 1536 +
                      512 + h * 64 + quad * 8;
      short8 kf0 = *(const short8*)kp;
      short8 kf1 = *(const short8*)(kp + 32);
      sacc[tile] = MFMA_BF16(qf0, kf0, sacc[tile]);
      sacc[tile] = MFMA_BF16(qf1, kf1, sacc[tile]);
    }
#pragma unroll
    for (int tile = 0; tile < 8; ++tile)
#pragma unroll
      for (int r = 0; r < 4; ++r)
        avg[tile][r] += __expf(sacc[tile][r] * 0.125f) * il[r];
  }
#pragma unroll
  for (int tile = 0; tile < 8; ++tile)
#pragma unroll
    for (int r = 0; r < 4; ++r)
      attnw[(size_t)(b * 1024 + q0 + quad * 4 + r) * 1024 + colbase + tile * 16 +
            l15] = avg[tile][r] * 0.125f;
}

// ---------------- host launch ----------------
extern "C" void kernel_launch(void* const* d_in, const int* in_sizes, int n_in,
                              void* d_out, int out_size, void* d_ws, size_t ws_size,
                              hipStream_t stream) {
  (void)in_sizes; (void)n_in; (void)out_size; (void)ws_size;
  const float* h   = (const float*)d_in[0];
  const float* g1  = (const float*)d_in[1];
  const float* be1 = (const float*)d_in[2];
  const float* wq  = (const float*)d_in[3];
  const float* bq  = (const float*)d_in[4];
  const float* wk  = (const float*)d_in[5];
  const float* bk  = (const float*)d_in[6];
  const float* wv  = (const float*)d_in[7];
  const float* bv  = (const float*)d_in[8];
  const float* wo  = (const float*)d_in[9];
  const float* bo  = (const float*)d_in[10];
  const float* g2  = (const float*)d_in[11];
  const float* be2 = (const float*)d_in[12];
  const float* w1  = (const float*)d_in[13];
  const float* b1  = (const float*)d_in[14];
  const float* w2  = (const float*)d_in[15];
  const float* b2  = (const float*)d_in[16];

  char* p = (char*)d_ws;
  auto carve = [&](size_t bytes) {
    char* r = p;
    p += (bytes + 255) & ~(size_t)255;
    return r;
  };
  u16*   wcat = (u16*)carve((size_t)1536 * 512 * 2);
  u16*   wob  = (u16*)carve((size_t)512 * 512 * 2);
  u16*   w1b  = (u16*)carve((size_t)1024 * 512 * 2);
  u16*   w2b  = (u16*)carve((size_t)512 * 1024 * 2);
  float* bcat = (float*)carve((size_t)1536 * 4);
  u16*   hn   = (u16*)carve((size_t)16384 * 512 * 2);
  u16*   qkvb = (u16*)carve((size_t)16384 * 1536 * 2);
  u16*   vTb  = (u16*)carve((size_t)16384 * 512 * 2);
  u16*   ctxb = (u16*)carve((size_t)16384 * 512 * 2);
  u16*   fb   = (u16*)carve((size_t)16384 * 512 * 2);
  u16*   gb   = (u16*)carve((size_t)16384 * 1024 * 2);
  float* linv = (float*)carve((size_t)16 * 8 * 1024 * 4);

  float* outh = (float*)d_out;
  float* outattn = outh + (size_t)16384 * 512;

  cast4_kernel<<<256, 256, 0, stream>>>(wq, wcat, 65536);
  cast4_kernel<<<256, 256, 0, stream>>>(wk, wcat + 512 * 512, 65536);
  cast4_kernel<<<256, 256, 0, stream>>>(wv, wcat + 2 * 512 * 512, 65536);
  cast4_kernel<<<256, 256, 0, stream>>>(wo, wob, 65536);
  cast4_kernel<<<512, 256, 0, stream>>>(w1, w1b, 131072);
  cast4_kernel<<<512, 256, 0, stream>>>(w2, w2b, 131072);
  hipMemcpyAsync(bcat, bq, 512 * 4, hipMemcpyDeviceToDevice, stream);
  hipMemcpyAsync(bcat + 512, bk, 512 * 4, hipMemcpyDeviceToDevice, stream);
  hipMemcpyAsync(bcat + 1024, bv, 512 * 4, hipMemcpyDeviceToDevice, stream);

  ln_kernel<<<16384, 128, 0, stream>>>(h, g1, be1, hn);
  gemm_bt_kernel<true, false, false><<<dim3(12, 128), 256, 0, stream>>>(
      hn, wcat, bcat, nullptr, qkvb, 1536, 512);
  vtrans_kernel<<<2048, 256, 0, stream>>>(qkvb, vTb);
  attn_ctx_kernel<<<dim3(8, 8, 16), 256, 0, stream>>>(qkvb, vTb, ctxb, linv);
  attn_avg_kernel<<<1024, 512, 0, stream>>>(qkvb, linv, outattn);
  gemm_bt_kernel<false, false, true><<<dim3(4, 128), 256, 0, stream>>>(
      ctxb, wob, bo, h, outh, 512, 512);
  ln_kernel<<<16384, 128, 0, stream>>>(outh, g2, be2, fb);
  gemm_bt_kernel<true, true, false><<<dim3(8, 128), 256, 0, stream>>>(
      fb, w1b, b1, nullptr, gb, 1024, 512);
  gemm_bt_kernel<false, false, true><<<dim3(4, 128), 256, 0, stream>>>(
      gb, w2b, b2, outh, outh, 512, 1024);
}

// Round 4
// 493.647 us; speedup vs baseline: 1.4832x; 1.1198x over previous
//
#include <hip/hip_runtime.h>

typedef unsigned short u16;
typedef __attribute__((ext_vector_type(8))) short short8;
typedef __attribute__((ext_vector_type(4))) float floatx4;
typedef __attribute__((ext_vector_type(16))) float floatx16;

#define MFMA_BF16(a, b, c) __builtin_amdgcn_mfma_f32_16x16x32_bf16((a), (b), (c), 0, 0, 0)
#define MFMA32(a, b, c) __builtin_amdgcn_mfma_f32_32x32x16_bf16((a), (b), (c), 0, 0, 0)

__device__ __forceinline__ u16 f2bf(float f) {
  unsigned b = __float_as_uint(f);
  b = b + 0x7FFFu + ((b >> 16) & 1u);
  return (u16)(b >> 16);
}

// async global->LDS, 16B/lane; lds ptr is wave-uniform base, lane i lands at +i*16B
__device__ __forceinline__ void gll16(const u16* g, u16* lds_uniform) {
  __builtin_amdgcn_global_load_lds(
      (const __attribute__((address_space(1))) void*)g,
      (__attribute__((address_space(3))) void*)lds_uniform, 16, 0, 0);
}

// ---------------- fp32 -> bf16 cast ----------------
__global__ __launch_bounds__(256) void cast4_kernel(const float* __restrict__ src,
                                                    u16* __restrict__ dst, int n4) {
  int i = blockIdx.x * 256 + threadIdx.x;
  if (i < n4) {
    float4 v = ((const float4*)src)[i];
    ushort4 o;
    o.x = f2bf(v.x); o.y = f2bf(v.y); o.z = f2bf(v.z); o.w = f2bf(v.w);
    ((ushort4*)dst)[i] = o;
  }
}

// ---------------- LayerNorm (D=512), fp32 in -> bf16 out ----------------
__global__ __launch_bounds__(128) void ln_kernel(const float* __restrict__ x,
                                                 const float* __restrict__ g,
                                                 const float* __restrict__ be,
                                                 u16* __restrict__ y) {
  int row = blockIdx.x, t = threadIdx.x;
  float4 v = ((const float4*)(x + (size_t)row * 512))[t];
  float s = v.x + v.y + v.z + v.w;
  float q = v.x * v.x + v.y * v.y + v.z * v.z + v.w * v.w;
#pragma unroll
  for (int off = 32; off > 0; off >>= 1) {
    s += __shfl_xor(s, off);
    q += __shfl_xor(q, off);
  }
  __shared__ float sb[2], qb[2];
  int w = t >> 6;
  if ((t & 63) == 0) { sb[w] = s; qb[w] = q; }
  __syncthreads();
  s = sb[0] + sb[1];
  q = qb[0] + qb[1];
  float mu = s * (1.0f / 512.0f);
  float var = q * (1.0f / 512.0f) - mu * mu;
  float rs = rsqrtf(var + 1e-5f);
  float4 gg = ((const float4*)g)[t];
  float4 bb = ((const float4*)be)[t];
  ushort4 o;
  o.x = f2bf((v.x - mu) * rs * gg.x + bb.x);
  o.y = f2bf((v.y - mu) * rs * gg.y + bb.y);
  o.z = f2bf((v.z - mu) * rs * gg.z + bb.z);
  o.w = f2bf((v.w - mu) * rs * gg.w + bb.w);
  ((ushort4*)(y + (size_t)row * 512))[t] = o;
}

// ---------------- m97-style MFMA GEMM ----------------
template <bool OUTB, bool SILU, bool RES>
__global__ __launch_bounds__(256) void gemm_bt_kernel(
    const u16* __restrict__ A, const u16* __restrict__ W,
    const float* __restrict__ bias, const float* __restrict__ res,
    void* __restrict__ out, int N, int K) {
  __shared__ __align__(16) u16 As[128 * 32];
  __shared__ __align__(16) u16 Bs[128 * 32];
  int t = threadIdx.x;
  int lane = t & 63, wave = t >> 6;
  int l15 = lane & 15, quad = lane >> 4;
  int rowBlk = blockIdx.y * 128, colBlk = blockIdx.x * 128;
  const u16* Ag = A + (size_t)(rowBlk + (t >> 2)) * K + (t & 3) * 8;
  const u16* Wg = W + (size_t)(colBlk + (t >> 2)) * K + (t & 3) * 8;
  u16* AsW = As + wave * 512;
  u16* BsW = Bs + wave * 512;
  int arow = (wave >> 1) * 64;
  int brow = (wave & 1) * 64;
  floatx4 acc[4][4] = {};
  for (int k0 = 0; k0 < K; k0 += 32) {
    gll16(Ag + k0, AsW);
    gll16(Ag + (size_t)64 * K + k0, AsW + 2048);
    gll16(Wg + k0, BsW);
    gll16(Wg + (size_t)64 * K + k0, BsW + 2048);
    __syncthreads();
    short8 a[4], b[4];
#pragma unroll
    for (int i = 0; i < 4; ++i)
      a[i] = *(const short8*)(As + (size_t)(arow + i * 16 + l15) * 32 + quad * 8);
#pragma unroll
    for (int j = 0; j < 4; ++j)
      b[j] = *(const short8*)(Bs + (size_t)(brow + j * 16 + l15) * 32 + quad * 8);
#pragma unroll
    for (int i = 0; i < 4; ++i)
#pragma unroll
      for (int j = 0; j < 4; ++j)
        acc[i][j] = MFMA_BF16(a[i], b[j], acc[i][j]);
    __syncthreads();
  }
#pragma unroll
  for (int j = 0; j < 4; ++j) {
    int col = colBlk + brow + j * 16 + l15;
    float bs = bias[col];
#pragma unroll
    for (int i = 0; i < 4; ++i) {
      int row0 = rowBlk + arow + i * 16 + quad * 4;
#pragma unroll
      for (int r = 0; r < 4; ++r) {
        size_t idx = (size_t)(row0 + r) * N + col;
        float v = acc[i][j][r] + bs;
        if (RES) v += res[idx];
        if (SILU) v = v * (1.0f / (1.0f + __expf(-v)));
        if (OUTB) ((u16*)out)[idx] = f2bf(v);
        else ((float*)out)[idx] = v;
      }
    }
  }
}

// ---------------- V transpose: qkv v-part -> vT [b][h][dh][n] ----------------
__global__ __launch_bounds__(256) void vtrans_kernel(const u16* __restrict__ qkv,
                                                     u16* __restrict__ vT) {
  __shared__ u16 tile[64][68];
  int blk = blockIdx.x;
  int b = blk >> 7, h = (blk >> 4) & 7, n0 = (blk & 15) * 64;
  int t = threadIdx.x;
#pragma unroll
  for (int rep = 0; rep < 16; ++rep) {
    int idx = t + rep * 256;
    int nl = idx >> 6, dh = idx & 63;
    tile[nl][dh] = qkv[(size_t)(b * 1024 + n0 + nl) * 1536 + 1024 + h * 64 + dh];
  }
  __syncthreads();
#pragma unroll
  for (int rep = 0; rep < 16; ++rep) {
    int idx = t + rep * 256;
    int dh = idx >> 6, nl = idx & 63;
    vT[((size_t)(b * 8 + h) * 64 + dh) * 1024 + n0 + nl] = tile[nl][dh];
  }
}

// ---------------- attention ctx: 32x32 MFMA + LDS dbuf staging ----------------
__global__ __launch_bounds__(256) void attn_ctx_kernel(const u16* __restrict__ qkv,
                                                       const u16* __restrict__ vT,
                                                       u16* __restrict__ ctx,
                                                       float* __restrict__ linv_g) {
  __shared__ __align__(16) u16 Kb[2][4096];
  __shared__ __align__(16) u16 Vb[2][4096];
  __shared__ __align__(16) u16 Pbuf[4][2048];
  int t = threadIdx.x, lane = t & 63, wave = t >> 6;
  int l31 = lane & 31, hi = lane >> 5;
  int b = blockIdx.z, h = blockIdx.y, q0w = blockIdx.x * 128 + wave * 32;
  u16* Pw = &Pbuf[wave][0];

  short8 qf[4];
  const u16* qbase = qkv + (size_t)(b * 1024 + q0w + l31) * 1536 + h * 64;
#pragma unroll
  for (int t4 = 0; t4 < 4; ++t4)
    qf[t4] = *(const short8*)(qbase + t4 * 16 + hi * 8);

  floatx16 oacc[2] = {};
  float rs[16];
#pragma unroll
  for (int r = 0; r < 16; ++r) rs[r] = 0.f;

  const u16* krow = qkv + (size_t)(b * 1024 + lane) * 1536 + 512 + h * 64;
  const u16* vrow = vT + ((size_t)(b * 8 + h) * 64 + lane) * 1024;

  gll16(krow + wave * 8, &Kb[0][wave * 512]);
  gll16(krow + (wave + 4) * 8, &Kb[0][(wave + 4) * 512]);
  gll16(vrow + wave * 8, &Vb[0][wave * 512]);
  gll16(vrow + (wave + 4) * 8, &Vb[0][(wave + 4) * 512]);
  __syncthreads();

#pragma unroll 1
  for (int c = 0; c < 16; ++c) {
    int bf = c & 1;
    if (c < 15) {
      int nc = (c + 1) * 64;
      gll16(krow + (size_t)nc * 1536 + wave * 8, &Kb[bf ^ 1][wave * 512]);
      gll16(krow + (size_t)nc * 1536 + (wave + 4) * 8, &Kb[bf ^ 1][(wave + 4) * 512]);
      gll16(vrow + nc + wave * 8, &Vb[bf ^ 1][wave * 512]);
      gll16(vrow + nc + (wave + 4) * 8, &Vb[bf ^ 1][(wave + 4) * 512]);
    }
    floatx16 sacc[2] = {};
#pragma unroll
    for (int ct = 0; ct < 2; ++ct)
#pragma unroll
      for (int t4 = 0; t4 < 4; ++t4) {
        short8 kf = *(const short8*)&Kb[bf][(t4 * 2 + hi) * 512 + (ct * 32 + l31) * 8];
        sacc[ct] = MFMA32(qf[t4], kf, sacc[ct]);
      }
#pragma unroll
    for (int ct = 0; ct < 2; ++ct) {
      int key = ct * 32 + l31;
      int g = key >> 3;
      int kb = key & 7;
#pragma unroll
      for (int reg = 0; reg < 16; ++reg) {
        int row = (reg & 3) + 8 * (reg >> 2) + 4 * hi;
        float e = __expf(sacc[ct][reg] * 0.125f);
        rs[reg] += e;
        Pw[g * 256 + ((row ^ g) << 3) + kb] = f2bf(e);
      }
    }
#pragma unroll
    for (int ks = 0; ks < 4; ++ks) {
      int g = ks * 2 + hi;
      short8 af = *(const short8*)&Pw[g * 256 + ((l31 ^ g) << 3)];
#pragma unroll
      for (int ct = 0; ct < 2; ++ct) {
        short8 vf = *(const short8*)&Vb[bf][g * 512 + (ct * 32 + l31) * 8];
        oacc[ct] = MFMA32(af, vf, oacc[ct]);
      }
    }
    __syncthreads();
  }

#pragma unroll
  for (int off = 1; off < 32; off <<= 1)
#pragma unroll
    for (int r = 0; r < 16; ++r) rs[r] += __shfl_xor(rs[r], off);
  float il[16];
#pragma unroll
  for (int r = 0; r < 16; ++r) il[r] = 1.0f / rs[r];
  if (l31 == 0) {
#pragma unroll
    for (int reg = 0; reg < 16; ++reg) {
      int row = (reg & 3) + 8 * (reg >> 2) + 4 * hi;
      linv_g[(size_t)(b * 8 + h) * 1024 + q0w + row] = il[reg];
    }
  }
#pragma unroll
  for (int ct = 0; ct < 2; ++ct)
#pragma unroll
    for (int reg = 0; reg < 16; ++reg) {
      int row = (reg & 3) + 8 * (reg >> 2) + 4 * hi;
      ctx[(size_t)(b * 1024 + q0w + row) * 512 + h * 64 + ct * 32 + l31] =
          f2bf(oacc[ct][reg] * il[reg]);
    }
}

// ---------------- averaged attention weights v2 ----------------
// grid (32, 16): x = kq*8 + qb (8 consecutive blocks share (kq,b) -> L2 reuse
// of K). block = 4 waves x 32 q-rows = 128 q-rows; key range kq*256..+255 in
// 4 chunks of 64. Iter = (chunk, h); K chunk staged block-wide via
// global_load_lds, double-buffered, 1 barrier/iter. avg = sum_h e*linv
// accumulated per chunk in regs (32 fp32/lane), stored once per chunk.
__global__ __launch_bounds__(256) void attn_avg_kernel(const u16* __restrict__ qkv,
                                                       const float* __restrict__ linv_g,
                                                       float* __restrict__ attnw) {
  __shared__ __align__(16) u16 Kb[2][4096];
  int t = threadIdx.x, lane = t & 63, wave = t >> 6;
  int l31 = lane & 31, hi = lane >> 5;
  int qb = blockIdx.x & 7, kq = blockIdx.x >> 3;
  int b = blockIdx.y;
  int q0w = qb * 128 + wave * 32;
  int key0 = kq * 256;

  const u16* qbase = qkv + (size_t)(b * 1024 + q0w + l31) * 1536;
  // staging source: lane = key within 64-chunk, gran = 8-dh granule
  const u16* kbase0 = qkv + (size_t)(b * 1024 + key0 + lane) * 1536 + 512;

  // prologue: iter 0 = (chunk 0, h 0) into buf 0
  gll16(kbase0 + wave * 8, &Kb[0][wave * 512]);
  gll16(kbase0 + (wave + 4) * 8, &Kb[0][(wave + 4) * 512]);
  __syncthreads();

  floatx16 avgacc[2] = {};
#pragma unroll 1
  for (int it = 0; it < 32; ++it) {
    int h = it & 7, chunk = it >> 3;
    int bf = it & 1;
    if (it < 31) {
      int nh = (it + 1) & 7, nc = (it + 1) >> 3;
      const u16* kb = kbase0 + (size_t)(nc * 64) * 1536 + nh * 64;
      gll16(kb + wave * 8, &Kb[bf ^ 1][wave * 512]);
      gll16(kb + (wave + 4) * 8, &Kb[bf ^ 1][(wave + 4) * 512]);
    }
    // Q frags for this head (L1-resident after first chunk)
    short8 qf[4];
#pragma unroll
    for (int t4 = 0; t4 < 4; ++t4)
      qf[t4] = *(const short8*)(qbase + h * 64 + t4 * 16 + hi * 8);
    // linv for my 16 C-layout rows
    const float* lg = linv_g + (size_t)(b * 8 + h) * 1024 + q0w + 4 * hi;
    float4 il0 = *(const float4*)(lg);
    float4 il1 = *(const float4*)(lg + 8);
    float4 il2 = *(const float4*)(lg + 16);
    float4 il3 = *(const float4*)(lg + 24);
    float il[16] = {il0.x, il0.y, il0.z, il0.w, il1.x, il1.y, il1.z, il1.w,
                    il2.x, il2.y, il2.z, il2.w, il3.x, il3.y, il3.z, il3.w};
    floatx16 sacc[2] = {};
#pragma unroll
    for (int ct = 0; ct < 2; ++ct)
#pragma unroll
      for (int t4 = 0; t4 < 4; ++t4) {
        short8 kf = *(const short8*)&Kb[bf][(t4 * 2 + hi) * 512 + (ct * 32 + l31) * 8];
        sacc[ct] = MFMA32(qf[t4], kf, sacc[ct]);
      }
#pragma unroll
    for (int ct = 0; ct < 2; ++ct)
#pragma unroll
      for (int r = 0; r < 16; ++r)
        avgacc[ct][r] += __expf(sacc[ct][r] * 0.125f) * il[r];
    __syncthreads();
    if (h == 7) {
      int cb = key0 + chunk * 64;
#pragma unroll
      for (int ct = 0; ct < 2; ++ct)
#pragma unroll
        for (int r = 0; r < 16; ++r) {
          int row = (r & 3) + 8 * (r >> 2) + 4 * hi;
          attnw[(size_t)(b * 1024 + q0w + row) * 1024 + cb + ct * 32 + l31] =
              avgacc[ct][r] * 0.125f;
          avgacc[ct][r] = 0.f;
        }
    }
  }
}

// ---------------- host launch ----------------
extern "C" void kernel_launch(void* const* d_in, const int* in_sizes, int n_in,
                              void* d_out, int out_size, void* d_ws, size_t ws_size,
                              hipStream_t stream) {
  (void)in_sizes; (void)n_in; (void)out_size; (void)ws_size;
  const float* h   = (const float*)d_in[0];
  const float* g1  = (const float*)d_in[1];
  const float* be1 = (const float*)d_in[2];
  const float* wq  = (const float*)d_in[3];
  const float* bq  = (const float*)d_in[4];
  const float* wk  = (const float*)d_in[5];
  const float* bk  = (const float*)d_in[6];
  const float* wv  = (const float*)d_in[7];
  const float* bv  = (const float*)d_in[8];
  const float* wo  = (const float*)d_in[9];
  const float* bo  = (const float*)d_in[10];
  const float* g2  = (const float*)d_in[11];
  const float* be2 = (const float*)d_in[12];
  const float* w1  = (const float*)d_in[13];
  const float* b1  = (const float*)d_in[14];
  const float* w2  = (const float*)d_in[15];
  const float* b2  = (const float*)d_in[16];

  char* p = (char*)d_ws;
  auto carve = [&](size_t bytes) {
    char* r = p;
    p += (bytes + 255) & ~(size_t)255;
    return r;
  };
  u16*   wcat = (u16*)carve((size_t)1536 * 512 * 2);
  u16*   wob  = (u16*)carve((size_t)512 * 512 * 2);
  u16*   w1b  = (u16*)carve((size_t)1024 * 512 * 2);
  u16*   w2b  = (u16*)carve((size_t)512 * 1024 * 2);
  float* bcat = (float*)carve((size_t)1536 * 4);
  u16*   hn   = (u16*)carve((size_t)16384 * 512 * 2);
  u16*   qkvb = (u16*)carve((size_t)16384 * 1536 * 2);
  u16*   vTb  = (u16*)carve((size_t)16384 * 512 * 2);
  u16*   ctxb = (u16*)carve((size_t)16384 * 512 * 2);
  u16*   fb   = (u16*)carve((size_t)16384 * 512 * 2);
  u16*   gb   = (u16*)carve((size_t)16384 * 1024 * 2);
  float* linv = (float*)carve((size_t)16 * 8 * 1024 * 4);

  float* outh = (float*)d_out;
  float* outattn = outh + (size_t)16384 * 512;

  cast4_kernel<<<256, 256, 0, stream>>>(wq, wcat, 65536);
  cast4_kernel<<<256, 256, 0, stream>>>(wk, wcat + 512 * 512, 65536);
  cast4_kernel<<<256, 256, 0, stream>>>(wv, wcat + 2 * 512 * 512, 65536);
  cast4_kernel<<<256, 256, 0, stream>>>(wo, wob, 65536);
  cast4_kernel<<<512, 256, 0, stream>>>(w1, w1b, 131072);
  cast4_kernel<<<512, 256, 0, stream>>>(w2, w2b, 131072);
  hipMemcpyAsync(bcat, bq, 512 * 4, hipMemcpyDeviceToDevice, stream);
  hipMemcpyAsync(bcat + 512, bk, 512 * 4, hipMemcpyDeviceToDevice, stream);
  hipMemcpyAsync(bcat + 1024, bv, 512 * 4, hipMemcpyDeviceToDevice, stream);

  ln_kernel<<<16384, 128, 0, stream>>>(h, g1, be1, hn);
  gemm_bt_kernel<true, false, false><<<dim3(12, 128), 256, 0, stream>>>(
      hn, wcat, bcat, nullptr, qkvb, 1536, 512);
  vtrans_kernel<<<2048, 256, 0, stream>>>(qkvb, vTb);
  attn_ctx_kernel<<<dim3(8, 8, 16), 256, 0, stream>>>(qkvb, vTb, ctxb, linv);
  attn_avg_kernel<<<dim3(32, 16), 256, 0, stream>>>(qkvb, linv, outattn);
  gemm_bt_kernel<false, false, true><<<dim3(4, 128), 256, 0, stream>>>(
      ctxb, wob, bo, h, outh, 512, 512);
  ln_kernel<<<16384, 128, 0, stream>>>(outh, g2, be2, fb);
  gemm_bt_kernel<true, true, false><<<dim3(8, 128), 256, 0, stream>>>(
      fb, w1b, b1, nullptr, gb, 1024, 512);
  gemm_bt_kernel<false, false, true><<<dim3(4, 128), 256, 0, stream>>>(
      gb, w2b, b2, outh, outh, 512, 1024);
}